// Round 8
// baseline (135.709 us; speedup 1.0000x reference)
//
#include <hip/hip_runtime.h>
#include <hip/hip_bf16.h>

typedef __bf16 bf16x8 __attribute__((ext_vector_type(8)));
typedef float  f32x4  __attribute__((ext_vector_type(4)));

#define LQ 4096
#define LKK 4096
#define DH 64
#define KBLK 32
#define QBLK 64
#define NIT (LKK / KBLK)        /* 128 KV tiles of 32 keys */
#define NB 4
#define GR_TILE 256             /* 16B granules per 32x64 bf16 tile */
#define ARR_ELEMS ((size_t)NB * NIT * GR_TILE * 8)   /* 1,048,576 */
#define KV_BYTES (4 * ARR_ELEMS * sizeof(__bf16))    /* 8 MB */
#define PO_BYTES(N)  ((size_t)(N) * 256 * QBLK * DH * sizeof(float))
#define PML_BYTES(N) ((size_t)(N) * 256 * 128 * sizeof(float))
#define WS_N(N) (KV_BYTES + PO_BYTES(N) + PML_BYTES(N))

typedef const __attribute__((address_space(1))) void* gas1_t;
typedef __attribute__((address_space(3))) void* las3_t;
__device__ __forceinline__ void gload_lds16(const void* g, void* l) {
    __builtin_amdgcn_global_load_lds((gas1_t)g, (las3_t)l, 16, 0, 0);
}

__device__ __forceinline__ unsigned cvt_pk_bf16(float a, float b) {
    unsigned r;
    asm volatile("v_cvt_pk_bf16_f32 %0, %1, %2" : "=v"(r) : "v"(a), "v"(b));
    return r;
}

// ---------------------------------------------------------------------------
// KBLK=32 fragment-linear granules (16B = one lane's ds_read_b128):
//   K (A-op of S^T=K Q^T): G=(kb*2+c)*64+ln, elem j = K[16kb+ll][32c+8gg+j]
//   V (A-op of O^T=V^T P^T): G=db*64+ln,     elem j = V[8gg+j][16db+ll]
// (gg=ln>>4, ll=ln&15).  Staging is lane-linear -> fits global_load_lds.
//
// PSM (per-wave P redistribution), row q=l15 of 32 u32 pair-words
// (hi quads 0-3 = keys 0..31, lo quads 4-7):
//   phys_quad = log_quad ^ sigma,  sigma = (q&3) ^ (2*(q>>2))
// Enumerated: b64 pair-writes and b128 reads are both 2 words/bank per
// 16-lane phase -> conflict-free (fixes r7's 16-bank even-word collapse).
// ---------------------------------------------------------------------------

__global__ __launch_bounds__(256)
void prepack(const float* __restrict__ Kg, const float* __restrict__ Vg,
             __bf16* __restrict__ ws)
{
    __bf16* KHI = ws;
    __bf16* KLO = ws + ARR_ELEMS;
    __bf16* VHI = ws + 2 * ARR_ELEMS;
    __bf16* VLO = ws + 3 * ARR_ELEMS;

    const int gid = blockIdx.x * 256 + threadIdx.x;   // [0, 262144)
    const int isV = gid >> 17;
    const int t   = gid & 131071;
    const int b   = t >> 15;
    const int rem = t & 32767;
    const int kt  = rem >> 8;        // [0,128)
    const int G   = rem & 255;
    const int gg  = (G >> 4) & 3;
    const int ll  = G & 15;

    const size_t dst = ((size_t)(b * NIT + kt) * GR_TILE + G) * 8;
    float x[8];
    if (!isV) {
        const int kb = G >> 7, c = (G >> 6) & 1;
        const float* src = Kg + ((size_t)b * LKK + kt * KBLK + 16 * kb + ll) * DH + 32 * c + 8 * gg;
        float4 a0 = *(const float4*)src;
        float4 a1 = *(const float4*)(src + 4);
        x[0]=a0.x; x[1]=a0.y; x[2]=a0.z; x[3]=a0.w;
        x[4]=a1.x; x[5]=a1.y; x[6]=a1.z; x[7]=a1.w;
        bf16x8 h, l;
#pragma unroll
        for (int j = 0; j < 8; ++j) {
            __bf16 hh = (__bf16)x[j];
            h[j] = hh; l[j] = (__bf16)(x[j] - (float)hh);
        }
        *(bf16x8*)&KHI[dst] = h;  *(bf16x8*)&KLO[dst] = l;
    } else {
        const int db = G >> 6;
        const float* src = Vg + ((size_t)b * LKK + kt * KBLK + 8 * gg) * DH + 16 * db + ll;
#pragma unroll
        for (int j = 0; j < 8; ++j) x[j] = src[(size_t)j * DH];
        bf16x8 h, l;
#pragma unroll
        for (int j = 0; j < 8; ++j) {
            __bf16 hh = (__bf16)x[j];
            h[j] = hh; l[j] = (__bf16)(x[j] - (float)hh);
        }
        *(bf16x8*)&VHI[dst] = h;  *(bf16x8*)&VLO[dst] = l;
    }
}

// ============ split-KV pass 1: 40KB LDS -> 4 blocks/CU, 16 waves/CU =========
template<int NSPLIT>
__global__ __launch_bounds__(256, 4)
void attn_split_t(const float* __restrict__ Qg, const __bf16* __restrict__ ws,
                  float* __restrict__ PO, float* __restrict__ PML)
{
    constexpr int LS  = (NSPLIT == 4) ? 2 : ((NSPLIT == 2) ? 1 : 0);
    constexpr int TPB = NIT / NSPLIT;
    const int bid = blockIdx.x;
    const int sp  = bid & (NSPLIT - 1);       // bid&7 spreads (sp,bz) over XCDs
    const int bz  = (bid >> LS) & 3;
    const int qt  = bid >> (LS + 2);
    const int pb  = sp * 256 + bz * 64 + qt;
    const int tid  = threadIdx.x;
    const int w    = tid >> 6;
    const int lane = tid & 63;
    const int g    = lane >> 4;
    const int l15  = lane & 15;
    const int q0   = qt * QBLK + w * 16;

    __shared__ __align__(16) __bf16 TILES[2][4][GR_TILE * 8];   // 32 KB
    __shared__ __align__(16) unsigned int PSM[4][16][32];       // 8 KB -> 40 KB total

    const __bf16* wsA[4] = { ws, ws + ARR_ELEMS, ws + 2 * ARR_ELEMS, ws + 3 * ARR_ELEMS };
    const size_t bqoff = (size_t)bz * LQ * DH;

    bf16x8 qhi[2], qlo[2];
#pragma unroll
    for (int c = 0; c < 2; ++c) {
        const float* src = Qg + bqoff + (size_t)(q0 + l15) * DH + 32 * c + 8 * g;
#pragma unroll
        for (int j = 0; j < 8; ++j) {
            float x = src[j] * 0.125f;
            __bf16 hh = (__bf16)x;
            qhi[c][j] = hh;
            qlo[c][j] = (__bf16)(x - (float)hh);
        }
    }
    bf16x8 vones;
#pragma unroll
    for (int j = 0; j < 8; ++j) vones[j] = (__bf16)1.0f;

    auto STAGE = [&](int buf, int kt) {
        const size_t toff = (size_t)(bz * NIT + kt) * GR_TILE * 8;
#pragma unroll
        for (int a = 0; a < 4; ++a) {
            const __bf16* src = wsA[a] + toff + (size_t)(w * 64 + lane) * 8;
            gload_lds16(src, &TILES[buf][a][w * 64 * 8]);
        }
    };

    f32x4 oacc[4] = {};
    f32x4 oext = {};                      // row-sums of P via ones-MFMA (= l)
    float m_run = -1e30f;

    const int kt0 = sp * TPB;
    STAGE(0, kt0);
    __syncthreads();

    int cur = 0;
    const int sig = (l15 & 3) ^ (((l15 >> 2) & 3) << 1);   // PSM swizzle

    for (int it = 0; it < TPB; ++it) {
        if (it + 1 < TPB) STAGE(cur ^ 1, kt0 + it + 1);

        const __bf16* KHI_l = TILES[cur][0];
        const __bf16* KLO_l = TILES[cur][1];
        const __bf16* VHI_l = TILES[cur][2];
        const __bf16* VLO_l = TILES[cur][3];

        // ---- S^T = K (Q*scale)^T ----
        f32x4 s[2] = {};
        __builtin_amdgcn_s_setprio(1);
#pragma unroll
        for (int kb = 0; kb < 2; ++kb) {
#pragma unroll
            for (int c = 0; c < 2; ++c) {
                bf16x8 kh = *(const bf16x8*)&KHI_l[((kb * 2 + c) * 64 + lane) * 8];
                bf16x8 kl = *(const bf16x8*)&KLO_l[((kb * 2 + c) * 64 + lane) * 8];
                s[kb] = __builtin_amdgcn_mfma_f32_16x16x32_bf16(kh, qhi[c], s[kb], 0, 0, 0);
                s[kb] = __builtin_amdgcn_mfma_f32_16x16x32_bf16(kh, qlo[c], s[kb], 0, 0, 0);
                s[kb] = __builtin_amdgcn_mfma_f32_16x16x32_bf16(kl, qhi[c], s[kb], 0, 0, 0);
            }
        }
        __builtin_amdgcn_s_setprio(0);

        // ---- online max (lane owns q=l15; 8 in-lane keys, reduce over g) ----
        float tmax = fmaxf(fmaxf(fmaxf(s[0][0], s[0][1]), fmaxf(s[0][2], s[0][3])),
                           fmaxf(fmaxf(s[1][0], s[1][1]), fmaxf(s[1][2], s[1][3])));
        tmax = fmaxf(tmax, __shfl_xor(tmax, 16, 64));
        tmax = fmaxf(tmax, __shfl_xor(tmax, 32, 64));

        const bool defer = __all(tmax <= m_run + 8.f);   // T13
        if (!defer) {
            float mnew = fmaxf(m_run, tmax);
            float alpha = __expf(m_run - mnew);
            m_run = mnew;
#pragma unroll
            for (int db = 0; db < 4; ++db) oacc[db] *= alpha;
            oext *= alpha;
        }

#pragma unroll
        for (int kb = 0; kb < 2; ++kb)
#pragma unroll
            for (int r = 0; r < 4; ++r)
                s[kb][r] = __expf(s[kb][r] - m_run);

        // ---- P -> PSM: b64 pair-writes, quad-XOR sigma swizzle ----
#pragma unroll
        for (int kb = 0; kb < 2; ++kb) {
            unsigned h0 = cvt_pk_bf16(s[kb][0], s[kb][1]);
            unsigned h1 = cvt_pk_bf16(s[kb][2], s[kb][3]);
            float l0 = s[kb][0] - __uint_as_float(h0 << 16);
            float l1 = s[kb][1] - __uint_as_float(h0 & 0xffff0000u);
            float l2 = s[kb][2] - __uint_as_float(h1 << 16);
            float l3 = s[kb][3] - __uint_as_float(h1 & 0xffff0000u);
            unsigned lo0 = cvt_pk_bf16(l0, l1);
            unsigned lo1 = cvt_pk_bf16(l2, l3);
            const int base = ((( (2 * kb + (g >> 1)) ^ sig) << 2) | ((g & 1) << 1));
            uint2 hh; hh.x = h0;  hh.y = h1;
            uint2 ll; ll.x = lo0; ll.y = lo1;
            *(uint2*)&PSM[w][l15][base]      = hh;
            *(uint2*)&PSM[w][l15][base ^ 16] = ll;
        }

        // ---- O^T += V^T P^T  (+ ones row-sum -> oext) ----
        {
            const int rbase = (g ^ sig) << 2;
            bf16x8 ph = *(const bf16x8*)&PSM[w][l15][rbase];
            bf16x8 pl = *(const bf16x8*)&PSM[w][l15][rbase ^ 16];
            __builtin_amdgcn_s_setprio(1);
#pragma unroll
            for (int db = 0; db < 4; ++db) {
                bf16x8 vh = *(const bf16x8*)&VHI_l[(db * 64 + lane) * 8];
                bf16x8 vl = *(const bf16x8*)&VLO_l[(db * 64 + lane) * 8];
                oacc[db] = __builtin_amdgcn_mfma_f32_16x16x32_bf16(vh, ph, oacc[db], 0, 0, 0);
                oacc[db] = __builtin_amdgcn_mfma_f32_16x16x32_bf16(vl, ph, oacc[db], 0, 0, 0);
                oacc[db] = __builtin_amdgcn_mfma_f32_16x16x32_bf16(vh, pl, oacc[db], 0, 0, 0);
            }
            oext = __builtin_amdgcn_mfma_f32_16x16x32_bf16(vones, ph, oext, 0, 0, 0);
            oext = __builtin_amdgcn_mfma_f32_16x16x32_bf16(vones, pl, oext, 0, 0, 0);
            __builtin_amdgcn_s_setprio(0);
        }

        __syncthreads();
        cur ^= 1;
    }

    // ---- epilogue: lane q = w*16+l15; oacc[db][r] = O^T[d=16db+4g+r][q] ----
    if constexpr (NSPLIT == 1) {
        float inv = 1.0f / oext[0];
        float* og = PO + bqoff + (size_t)(q0 + l15) * DH;
#pragma unroll
        for (int db = 0; db < 4; ++db) {
            f32x4 v = oacc[db] * inv;
            *(f32x4*)&og[16 * db + 4 * g] = v;
        }
    } else {
        float* po = PO + (size_t)pb * (QBLK * DH) + (size_t)(w * 16 + l15) * DH;
#pragma unroll
        for (int db = 0; db < 4; ++db)
            *(f32x4*)&po[16 * db + 4 * g] = oacc[db];
        if (g == 0) {
            PML[pb * 128 + w * 16 + l15]      = m_run;
            PML[pb * 128 + 64 + w * 16 + l15] = oext[0];
        }
    }
}

template<int NSPLIT>
__global__ __launch_bounds__(256)
void combine_t(const float* __restrict__ PO, const float* __restrict__ PML,
               float* __restrict__ Og)
{
    const int t   = blockIdx.x * 256 + threadIdx.x;   // [0, 1048576)
    const int d   = t & 63;
    const int row = (t >> 6) & 4095;
    const int bz  = t >> 18;
    const int qt  = row >> 6, ri = row & 63;
    float m[NSPLIT], l[NSPLIT], o[NSPLIT];
    float M = -1e30f;
#pragma unroll
    for (int i = 0; i < NSPLIT; ++i) {
        const int pbi = i * 256 + bz * 64 + qt;
        m[i] = PML[pbi * 128 + ri];
        l[i] = PML[pbi * 128 + 64 + ri];
        o[i] = PO[(size_t)pbi * 4096 + ri * 64 + d];
        M = fmaxf(M, m[i]);
    }
    float num = 0.f, den = 0.f;
#pragma unroll
    for (int i = 0; i < NSPLIT; ++i) {
        float a = __expf(m[i] - M);
        num += a * o[i];
        den += a * l[i];
    }
    Og[t] = num / den;
}

extern "C" void kernel_launch(void* const* d_in, const int* in_sizes, int n_in,
                              void* d_out, int out_size, void* d_ws, size_t ws_size,
                              hipStream_t stream) {
    (void)in_sizes; (void)n_in; (void)out_size;
    const float* Q = (const float*)d_in[0];
    const float* K = (const float*)d_in[1];
    const float* V = (const float*)d_in[2];
    float* O = (float*)d_out;
    __bf16* ws = (__bf16*)d_ws;

    prepack<<<dim3(1024), dim3(256), 0, stream>>>(K, V, ws);

    if (ws_size >= WS_N(4)) {
        float* PO  = (float*)((char*)d_ws + KV_BYTES);
        float* PML = (float*)((char*)d_ws + KV_BYTES + PO_BYTES(4));
        attn_split_t<4><<<dim3(1024), dim3(256), 0, stream>>>(Q, ws, PO, PML);
        combine_t<4><<<dim3(4096), dim3(256), 0, stream>>>(PO, PML, O);
    } else if (ws_size >= WS_N(2)) {
        float* PO  = (float*)((char*)d_ws + KV_BYTES);
        float* PML = (float*)((char*)d_ws + KV_BYTES + PO_BYTES(2));
        attn_split_t<2><<<dim3(512), dim3(256), 0, stream>>>(Q, ws, PO, PML);
        combine_t<2><<<dim3(4096), dim3(256), 0, stream>>>(PO, PML, O);
    } else {
        attn_split_t<1><<<dim3(256), dim3(256), 0, stream>>>(Q, ws, O, nullptr);
    }
}